// Round 13
// baseline (325.575 us; speedup 1.0000x reference)
//
#include <hip/hip_runtime.h>

#define D 64
#define N_USERS 100000
#define N_ITEMS 50000
#define RW 64                              // rows per bucket
#define B_UI ((N_ITEMS + RW - 1) / RW)     // 782 item buckets
#define B_IU ((N_USERS + RW - 1) / RW)     // 1563 user buckets
#define B_TOT (B_UI + B_IU)                // 2345
#define CHUNK 8192                         // edges per scatter block (== 8 * SCT_THREADS)
#define SCT_THREADS 1024                   // scatter block threads (round-6 proven)
#define P2_THREADS 512                     // pass-2 threads (round-7 proven)
#define TILE 4096                          // pass-2 edge tile (round-7 proven)

static inline size_t align16(size_t x) { return (x + 15) & ~(size_t)15; }

// fp32 -> bf16 (RNE), packed two per uint (elem 2k low, 2k+1 high)
__device__ inline unsigned int bf16rne(float f) {
    unsigned int b = __float_as_uint(f);
    return (b + 0x7fffu + ((b >> 16) & 1u)) >> 16;
}
__device__ inline float bf16lo(unsigned int u) { return __uint_as_float(u << 16); }
__device__ inline float bf16hi(unsigned int u) { return __uint_as_float(u & 0xffff0000u); }

// ---------------- kernel A: fp32->bf16 convert + bucket totals (fused, r8) -------
__global__ __launch_bounds__(256) void convert_count_kernel(
        const float* __restrict__ user_feat, const float* __restrict__ item_feat,
        unsigned int* __restrict__ user16, unsigned int* __restrict__ item16,
        const int* __restrict__ ui_dst, const int* __restrict__ iu_dst,
        int* __restrict__ totals, int n_ui, long long n_total) {
    __shared__ int hist[B_TOT];
    for (int b = threadIdx.x; b < B_TOT; b += blockDim.x) hist[b] = 0;
    __syncthreads();

    const long long USER_ELEMS = (long long)N_USERS * D;
    const long long TOTAL = USER_ELEMS + (long long)N_ITEMS * D;
    {
        long long i4 = ((long long)blockIdx.x * blockDim.x + threadIdx.x) * 4;
        const long long stride = (long long)gridDim.x * blockDim.x * 4;
        for (; i4 < TOTAL; i4 += stride) {
            const float4 v = (i4 < USER_ELEMS)
                ? *(const float4*)(user_feat + i4)
                : *(const float4*)(item_feat + (i4 - USER_ELEMS));
            uint2 p;
            p.x = bf16rne(v.x) | (bf16rne(v.y) << 16);
            p.y = bf16rne(v.z) | (bf16rne(v.w) << 16);
            unsigned int* dst = (i4 < USER_ELEMS) ? (user16 + (i4 >> 1))
                                                  : (item16 + ((i4 - USER_ELEMS) >> 1));
            *(uint2*)dst = p;
        }
    }
    {
        long long i = (long long)blockIdx.x * blockDim.x + threadIdx.x;
        const long long stride = (long long)gridDim.x * blockDim.x;
        for (; i < n_total; i += stride) {
            const int b = (i < n_ui) ? (ui_dst[i] >> 6)
                                     : B_UI + (iu_dst[i - n_ui] >> 6);
            atomicAdd(&hist[b], 1);
        }
    }
    __syncthreads();
    for (int b = threadIdx.x; b < B_TOT; b += blockDim.x) {
        const int c = hist[b];
        if (c) atomicAdd(&totals[b], c);
    }
}

// ---------------- kernel B: scan + reserve + scatter (single-pass edge reads) ----
// r12 PROVEN (-37us vs r8): each thread owns 8 edges, loaded ONCE into registers
// (statically unrolled) during the count phase; scatter runs from registers.
// nt-LOADS on streamed edge arrays (loads are fine on gfx950; nt-STORES are not).
__global__ __launch_bounds__(SCT_THREADS) void p1_scan_scatter_kernel(
        const int* __restrict__ ui_src, const int* __restrict__ iu_src,
        const int* __restrict__ ui_dst, const int* __restrict__ iu_dst,
        const float* __restrict__ norm_ui, const float* __restrict__ norm_iu,
        const int* __restrict__ totals,
        int* __restrict__ base,           // out: [B_TOT+1] (block 0 writes)
        int* __restrict__ gcur0,          // zero-initialized relative cursors
        long long* __restrict__ part,
        int n_ui, int n_iu, int NB_ui) {
    __shared__ int lcnt[B_TOT];
    __shared__ int lcur[B_TOT];          // scan result (base), then absolute cursor
    __shared__ int lds[1024];
    const int tid = threadIdx.x;

    // --- redundant per-block exclusive scan of totals -> lcur (=base) ---
    {
        int v0, v1, v2;
        const int i0 = tid * 3;
        v0 = (i0 + 0 < B_TOT) ? totals[i0 + 0] : 0;
        v1 = (i0 + 1 < B_TOT) ? totals[i0 + 1] : 0;
        v2 = (i0 + 2 < B_TOT) ? totals[i0 + 2] : 0;
        const int s = v0 + v1 + v2;
        lds[tid] = s;
        __syncthreads();
        for (int off = 1; off < 1024; off <<= 1) {
            int x = (tid >= off) ? lds[tid - off] : 0;
            __syncthreads();
            lds[tid] += x;
            __syncthreads();
        }
        int run = lds[tid] - s;
        const bool pub = (blockIdx.x == 0);
        if (i0 + 0 < B_TOT) { lcur[i0 + 0] = run; if (pub) base[i0 + 0] = run; } else if (i0 + 0 == B_TOT && pub) base[B_TOT] = run;
        run += v0;
        if (i0 + 1 < B_TOT) { lcur[i0 + 1] = run; if (pub) base[i0 + 1] = run; } else if (i0 + 1 == B_TOT && pub) base[B_TOT] = run;
        run += v1;
        if (i0 + 2 < B_TOT) { lcur[i0 + 2] = run; if (pub) base[i0 + 2] = run; } else if (i0 + 2 == B_TOT && pub) base[B_TOT] = run;
    }
    for (int b = tid; b < B_TOT; b += SCT_THREADS) lcnt[b] = 0;
    __syncthreads();

    const int blk = blockIdx.x;
    const bool is_ui = blk < NB_ui;
    const int* src = is_ui ? ui_src : iu_src;
    const int* dst = is_ui ? ui_dst : iu_dst;
    const float* nrm = is_ui ? norm_ui : norm_iu;
    const int n = is_ui ? n_ui : n_iu;
    const int boff = is_ui ? 0 : B_UI;
    const int e0 = (is_ui ? blk : blk - NB_ui) * CHUNK;

    // --- phase 1: load 8 edges/thread into registers + LDS count ---
    int d8[CHUNK / SCT_THREADS];
    int s8[CHUNK / SCT_THREADS];
    float nv8[CHUNK / SCT_THREADS];
#pragma unroll
    for (int k = 0; k < CHUNK / SCT_THREADS; k++) {
        const int t = e0 + k * SCT_THREADS + tid;
        if (t < n) {
            d8[k]  = __builtin_nontemporal_load(&dst[t]);
            s8[k]  = __builtin_nontemporal_load(&src[t]);
            nv8[k] = __builtin_nontemporal_load(&nrm[t]);
            atomicAdd(&lcnt[boff + (d8[k] >> 6)], 1);
        } else {
            d8[k] = -1;
        }
    }
    __syncthreads();

    // --- phase 2: reserve: absolute cursor = base + relative reservation ---
    for (int b = tid; b < B_TOT; b += SCT_THREADS) {
        const int c = lcnt[b];
        if (c) lcur[b] += atomicAdd(&gcur0[b], c);
    }
    __syncthreads();

    // --- phase 3: scatter from registers (no edge re-read; CACHED stores) ---
#pragma unroll
    for (int k = 0; k < CHUNK / SCT_THREADS; k++) {
        if (d8[k] >= 0) {
            const int d = d8[k];
            const int pos = atomicAdd(&lcur[boff + (d >> 6)], 1);
            const unsigned int lo = (unsigned int)(s8[k] | ((d & 63) << 26));
            const unsigned int hi = (unsigned int)__float_as_int(nv8[k]);
            part[pos] = (long long)(((unsigned long long)hi << 32) | lo);
        }
    }
}

// ---------------- pass 2: fused LDS counting-sort + gather --------------------
// Round-13: SURGICAL REVERT of r12's output nt-store (WRITE_SIZE doubled 37.5->
// 78.2 MB, p2 +24us -- gfx950 nt-stores defeat write-combining even when
// coalesced; rule: nt-LOADS ok, nt-STORES never). 8-deep loop shape kept from
// r12 (neutral: compiler collapsed it, VGPR stayed 40).
__global__ __launch_bounds__(P2_THREADS, 6) void p2_gather_kernel(
        const uint4* __restrict__ user16, const uint4* __restrict__ item16,
        const long long* __restrict__ part, const int* __restrict__ base,
        float* __restrict__ h_user, float* __restrict__ h_item) {
    __shared__ int2 sorted[TILE];        // 32 KB
    __shared__ float acc[RW * D];        // 16 KB
    __shared__ int cnt[RW], offs[RW], cursor[RW], cnt2[RW];
    const int b = blockIdx.x;
    const int tid = threadIdx.x;
    const int lane = tid & 63;
    const int wave = tid >> 6;           // 0..7

    const int E0 = base[b];
    const int E1 = base[b + 1];

    const bool item_side = b < B_UI;
    const uint4* __restrict__ feat = item_side ? user16 : item16;
    const int baseRow = (item_side ? b : b - B_UI) * RW;

    for (int i = tid; i < RW * D; i += P2_THREADS) acc[i] = 0.f;

    for (int bas = E0; bas < E1; bas += TILE) {
        const int tileN = min(TILE, E1 - bas);
        if (tid < RW) cnt[tid] = 0;
        __syncthreads();                           // A: acc/sorted free, cnt zeroed
        int2 v[TILE / P2_THREADS];
#pragma unroll
        for (int k = 0; k < TILE / P2_THREADS; k++) {
            const int t = tid + k * P2_THREADS;
            if (t < tileN) {
                const long long raw = __builtin_nontemporal_load(&part[bas + t]);
                v[k].x = (int)(unsigned int)(raw & 0xffffffffll);
                v[k].y = (int)(unsigned int)((unsigned long long)raw >> 32);
                atomicAdd(&cnt[((unsigned)v[k].x) >> 26], 1);
            }
        }
        __syncthreads();                           // B
        if (tid < RW) {  // wave 0 scans 64 counts
            const int c = cnt[tid];
            int incl = c;
            for (int dd = 1; dd < RW; dd <<= 1) {
                const int u = __shfl_up(incl, dd, 64);
                if (lane >= dd) incl += u;
            }
            offs[tid] = incl - c;
            cursor[tid] = incl - c;
            cnt2[tid] = c;
        }
        __syncthreads();                           // C
#pragma unroll
        for (int k = 0; k < TILE / P2_THREADS; k++) {
            const int t = tid + k * P2_THREADS;
            if (t < tileN) {
                const int r6 = ((unsigned)v[k].x) >> 26;
                const int pos = atomicAdd(&cursor[r6], 1);
                sorted[pos] = v[k];
            }
        }
        __syncthreads();                           // D
        for (int r = wave; r < RW; r += 8) {
            const int s = offs[r], c = cnt2[r];
            if (c == 0) continue;
            const int sub = lane & 7;
            const int g = lane >> 3;
            float a0 = 0, a1 = 0, a2 = 0, a3 = 0, a4 = 0, a5 = 0, a6 = 0, a7 = 0;
            // 8-deep pipeline: 8 independent feature lines in flight per lane.
            // Tail slots: zero-norm dummies (0 * finite == 0, exact no-op).
            for (int j = g; j < c; j += 64) {
                int2 e[8];
                uint4 f[8];
#pragma unroll
                for (int m = 0; m < 8; m++) {
                    const int idx = j + 8 * m;
                    e[m] = (idx < c) ? sorted[s + idx] : make_int2(0, 0);
                }
#pragma unroll
                for (int m = 0; m < 8; m++) {
                    f[m] = feat[(e[m].x & 0x03FFFFFF) * 8 + sub];
                }
#pragma unroll
                for (int m = 0; m < 8; m++) {
                    const float nv = __int_as_float(e[m].y);
                    a0 = fmaf(nv, bf16lo(f[m].x), a0);
                    a1 = fmaf(nv, bf16hi(f[m].x), a1);
                    a2 = fmaf(nv, bf16lo(f[m].y), a2);
                    a3 = fmaf(nv, bf16hi(f[m].y), a3);
                    a4 = fmaf(nv, bf16lo(f[m].z), a4);
                    a5 = fmaf(nv, bf16hi(f[m].z), a5);
                    a6 = fmaf(nv, bf16lo(f[m].w), a6);
                    a7 = fmaf(nv, bf16hi(f[m].w), a7);
                }
            }
            // reduce across the 8 edge-groups (lane bits 3..5)
            for (int m = 8; m <= 32; m <<= 1) {
                a0 += __shfl_xor(a0, m, 64);
                a1 += __shfl_xor(a1, m, 64);
                a2 += __shfl_xor(a2, m, 64);
                a3 += __shfl_xor(a3, m, 64);
                a4 += __shfl_xor(a4, m, 64);
                a5 += __shfl_xor(a5, m, 64);
                a6 += __shfl_xor(a6, m, 64);
                a7 += __shfl_xor(a7, m, 64);
            }
            if (lane < 8) {
                float4* ap = (float4*)&acc[r * D + lane * 8];
                float4 q0 = ap[0], q1 = ap[1];
                q0.x += a0; q0.y += a1; q0.z += a2; q0.w += a3;
                q1.x += a4; q1.y += a5; q1.z += a6; q1.w += a7;
                ap[0] = q0; ap[1] = q1;
            }
        }
    }
    __syncthreads();
    // write out 64 rows x 64 floats, coalesced float4, CACHED (r12: nt doubled WRITE)
    float* __restrict__ outp = item_side ? h_item : h_user;
    const int limit = item_side ? N_ITEMS : N_USERS;
#pragma unroll
    for (int it = 0; it < 1024 / P2_THREADS; it++) {
        const int i4 = tid + it * P2_THREADS;   // float4 index in [0,1024)
        const int r = (i4 * 4) >> 6;
        const int row = baseRow + r;
        if (row < limit) {
            *(float4*)&outp[(long long)row * D + ((i4 * 4) & 63)] = *(float4*)&acc[i4 * 4];
        }
    }
}

// ---------------- fallback: atomic scatter (round-1 proven) ----------------
__global__ void scatter_rel_kernel(const float* __restrict__ feat,
                                   const float* __restrict__ norm,
                                   const int* __restrict__ src,
                                   const int* __restrict__ dst,
                                   float* __restrict__ out, int n_edges) {
    const int lane = threadIdx.x & 63;
    const int wib = threadIdx.x >> 6;
    const int wpb = blockDim.x >> 6;
    long long e = (long long)blockIdx.x * wpb + wib;
    const long long stride = (long long)gridDim.x * wpb;
    for (; e < n_edges; e += stride) {
        atomicAdd(&out[(long long)dst[e] * D + lane],
                  norm[e] * feat[(long long)src[e] * D + lane]);
    }
}

extern "C" void kernel_launch(void* const* d_in, const int* in_sizes, int n_in,
                              void* d_out, int out_size, void* d_ws, size_t ws_size,
                              hipStream_t stream) {
    const float* user_feat = (const float*)d_in[0];
    const float* item_feat = (const float*)d_in[1];
    const float* norm_ui   = (const float*)d_in[2];
    const float* norm_iu   = (const float*)d_in[3];
    const int*   ui_src    = (const int*)d_in[4];  // user idx
    const int*   ui_dst    = (const int*)d_in[5];  // item idx
    const int*   iu_src    = (const int*)d_in[6];  // item idx
    const int*   iu_dst    = (const int*)d_in[7];  // user idx

    const int n_ui = in_sizes[4];
    const int n_iu = in_sizes[6];
    const int n_total = n_ui + n_iu;

    float* h_user = (float*)d_out;                              // [N_USERS, D]
    float* h_item = (float*)d_out + (long long)N_USERS * D;     // [N_ITEMS, D]

    const int block = 256;
    const int NB_ui = (n_ui + CHUNK - 1) / CHUNK;
    const int NB_iu = (n_iu + CHUNK - 1) / CHUNK;
    const int NCH = NB_ui + NB_iu;

    // ---- workspace layout (totals+gcur0 adjacent -> single memset) ----
    char* ws = (char*)d_ws;
    size_t off = 0;
    int* totals = (int*)(ws + off);  off += align16((size_t)B_TOT * 4);
    int* gcur0  = (int*)(ws + off);  off += align16((size_t)B_TOT * 4);
    int* base   = (int*)(ws + off);  off += align16((size_t)(B_TOT + 1) * 4);
    long long* part = (long long*)(ws + off); off += align16((size_t)n_total * 8);
    unsigned int* user16 = (unsigned int*)(ws + off); off += align16((size_t)N_USERS * D * 2);
    unsigned int* item16 = (unsigned int*)(ws + off); off += align16((size_t)N_ITEMS * D * 2);
    const size_t needed = off;

    if (ws_size < needed) {
        // fallback: atomic-scatter path
        (void)hipMemsetAsync(d_out, 0, (size_t)out_size * sizeof(float), stream);
        const int wpb = block / 64;
        scatter_rel_kernel<<<(n_ui + wpb - 1) / wpb, block, 0, stream>>>(
            user_feat, norm_ui, ui_src, ui_dst, h_item, n_ui);
        scatter_rel_kernel<<<(n_iu + wpb - 1) / wpb, block, 0, stream>>>(
            item_feat, norm_iu, iu_src, iu_dst, h_user, n_iu);
        return;
    }

    // zero totals + gcur0 in one memset (adjacent in layout)
    (void)hipMemsetAsync(totals, 0, ((size_t)align16((size_t)B_TOT * 4) + (size_t)B_TOT * 4), stream);

    // A. fused convert + bucket totals
    convert_count_kernel<<<512, block, 0, stream>>>(
        user_feat, item_feat, user16, item16, ui_dst, iu_dst,
        totals, n_ui, (long long)n_total);

    // B. fused scan + reserve + scatter (grid == NCH, edges register-cached)
    p1_scan_scatter_kernel<<<NCH, SCT_THREADS, 0, stream>>>(
        ui_src, iu_src, ui_dst, iu_dst, norm_ui, norm_iu,
        totals, base, gcur0, part, n_ui, n_iu, NB_ui);

    // C. fused sort+gather, one block per bucket (writes every output row)
    p2_gather_kernel<<<B_TOT, P2_THREADS, 0, stream>>>(
        (const uint4*)user16, (const uint4*)item16, part, base,
        h_user, h_item);
}

// Round 14
// 303.559 us; speedup vs baseline: 1.0725x; 1.0725x over previous
//
#include <hip/hip_runtime.h>

#define D 64
#define N_USERS 100000
#define N_ITEMS 50000
#define RW 64                              // rows per bucket
#define B_UI ((N_ITEMS + RW - 1) / RW)     // 782 item buckets
#define B_IU ((N_USERS + RW - 1) / RW)     // 1563 user buckets
#define B_TOT (B_UI + B_IU)                // 2345
#define CHUNK 8192                         // edges per scatter block (== 8 * SCT_THREADS)
#define SCT_THREADS 1024                   // scatter block threads (round-6 proven)
#define P2_THREADS 512                     // pass-2 threads (round-7 proven)
#define TILE 4096                          // pass-2 edge tile (round-7 proven)

static inline size_t align16(size_t x) { return (x + 15) & ~(size_t)15; }

// fp32 -> bf16 (RNE), packed two per uint (elem 2k low, 2k+1 high)
__device__ inline unsigned int bf16rne(float f) {
    unsigned int b = __float_as_uint(f);
    return (b + 0x7fffu + ((b >> 16) & 1u)) >> 16;
}
__device__ inline float bf16lo(unsigned int u) { return __uint_as_float(u << 16); }
__device__ inline float bf16hi(unsigned int u) { return __uint_as_float(u & 0xffff0000u); }

// ---------------- kernel A: fp32->bf16 convert + bucket totals (fused, r8) -------
__global__ __launch_bounds__(256) void convert_count_kernel(
        const float* __restrict__ user_feat, const float* __restrict__ item_feat,
        unsigned int* __restrict__ user16, unsigned int* __restrict__ item16,
        const int* __restrict__ ui_dst, const int* __restrict__ iu_dst,
        int* __restrict__ totals, int n_ui, long long n_total) {
    __shared__ int hist[B_TOT];
    for (int b = threadIdx.x; b < B_TOT; b += blockDim.x) hist[b] = 0;
    __syncthreads();

    const long long USER_ELEMS = (long long)N_USERS * D;
    const long long TOTAL = USER_ELEMS + (long long)N_ITEMS * D;
    {
        long long i4 = ((long long)blockIdx.x * blockDim.x + threadIdx.x) * 4;
        const long long stride = (long long)gridDim.x * blockDim.x * 4;
        for (; i4 < TOTAL; i4 += stride) {
            const float4 v = (i4 < USER_ELEMS)
                ? *(const float4*)(user_feat + i4)
                : *(const float4*)(item_feat + (i4 - USER_ELEMS));
            uint2 p;
            p.x = bf16rne(v.x) | (bf16rne(v.y) << 16);
            p.y = bf16rne(v.z) | (bf16rne(v.w) << 16);
            unsigned int* dst = (i4 < USER_ELEMS) ? (user16 + (i4 >> 1))
                                                  : (item16 + ((i4 - USER_ELEMS) >> 1));
            *(uint2*)dst = p;
        }
    }
    {
        long long i = (long long)blockIdx.x * blockDim.x + threadIdx.x;
        const long long stride = (long long)gridDim.x * blockDim.x;
        for (; i < n_total; i += stride) {
            const int b = (i < n_ui) ? (ui_dst[i] >> 6)
                                     : B_UI + (iu_dst[i - n_ui] >> 6);
            atomicAdd(&hist[b], 1);
        }
    }
    __syncthreads();
    for (int b = threadIdx.x; b < B_TOT; b += blockDim.x) {
        const int c = hist[b];
        if (c) atomicAdd(&totals[b], c);
    }
}

// ---------------- kernel B: scan + reserve + scatter (single-pass edge reads) ----
// r12 PROVEN (-37us vs r8): each thread owns 8 edges, loaded ONCE into registers
// (statically unrolled) during the count phase; scatter runs from registers.
// nt-LOADS on streamed edge arrays (loads fine on gfx950; nt-STORES never).
__global__ __launch_bounds__(SCT_THREADS) void p1_scan_scatter_kernel(
        const int* __restrict__ ui_src, const int* __restrict__ iu_src,
        const int* __restrict__ ui_dst, const int* __restrict__ iu_dst,
        const float* __restrict__ norm_ui, const float* __restrict__ norm_iu,
        const int* __restrict__ totals,
        int* __restrict__ base,           // out: [B_TOT+1] (block 0 writes)
        int* __restrict__ gcur0,          // zero-initialized relative cursors
        long long* __restrict__ part,
        int n_ui, int n_iu, int NB_ui) {
    __shared__ int lcnt[B_TOT];
    __shared__ int lcur[B_TOT];          // scan result (base), then absolute cursor
    __shared__ int lds[1024];
    const int tid = threadIdx.x;

    // --- redundant per-block exclusive scan of totals -> lcur (=base) ---
    {
        int v0, v1, v2;
        const int i0 = tid * 3;
        v0 = (i0 + 0 < B_TOT) ? totals[i0 + 0] : 0;
        v1 = (i0 + 1 < B_TOT) ? totals[i0 + 1] : 0;
        v2 = (i0 + 2 < B_TOT) ? totals[i0 + 2] : 0;
        const int s = v0 + v1 + v2;
        lds[tid] = s;
        __syncthreads();
        for (int off = 1; off < 1024; off <<= 1) {
            int x = (tid >= off) ? lds[tid - off] : 0;
            __syncthreads();
            lds[tid] += x;
            __syncthreads();
        }
        int run = lds[tid] - s;
        const bool pub = (blockIdx.x == 0);
        if (i0 + 0 < B_TOT) { lcur[i0 + 0] = run; if (pub) base[i0 + 0] = run; } else if (i0 + 0 == B_TOT && pub) base[B_TOT] = run;
        run += v0;
        if (i0 + 1 < B_TOT) { lcur[i0 + 1] = run; if (pub) base[i0 + 1] = run; } else if (i0 + 1 == B_TOT && pub) base[B_TOT] = run;
        run += v1;
        if (i0 + 2 < B_TOT) { lcur[i0 + 2] = run; if (pub) base[i0 + 2] = run; } else if (i0 + 2 == B_TOT && pub) base[B_TOT] = run;
    }
    for (int b = tid; b < B_TOT; b += SCT_THREADS) lcnt[b] = 0;
    __syncthreads();

    const int blk = blockIdx.x;
    const bool is_ui = blk < NB_ui;
    const int* src = is_ui ? ui_src : iu_src;
    const int* dst = is_ui ? ui_dst : iu_dst;
    const float* nrm = is_ui ? norm_ui : norm_iu;
    const int n = is_ui ? n_ui : n_iu;
    const int boff = is_ui ? 0 : B_UI;
    const int e0 = (is_ui ? blk : blk - NB_ui) * CHUNK;

    // --- phase 1: load 8 edges/thread into registers + LDS count ---
    int d8[CHUNK / SCT_THREADS];
    int s8[CHUNK / SCT_THREADS];
    float nv8[CHUNK / SCT_THREADS];
#pragma unroll
    for (int k = 0; k < CHUNK / SCT_THREADS; k++) {
        const int t = e0 + k * SCT_THREADS + tid;
        if (t < n) {
            d8[k]  = __builtin_nontemporal_load(&dst[t]);
            s8[k]  = __builtin_nontemporal_load(&src[t]);
            nv8[k] = __builtin_nontemporal_load(&nrm[t]);
            atomicAdd(&lcnt[boff + (d8[k] >> 6)], 1);
        } else {
            d8[k] = -1;
        }
    }
    __syncthreads();

    // --- phase 2: reserve: absolute cursor = base + relative reservation ---
    for (int b = tid; b < B_TOT; b += SCT_THREADS) {
        const int c = lcnt[b];
        if (c) lcur[b] += atomicAdd(&gcur0[b], c);
    }
    __syncthreads();

    // --- phase 3: scatter from registers (no edge re-read; CACHED stores) ---
#pragma unroll
    for (int k = 0; k < CHUNK / SCT_THREADS; k++) {
        if (d8[k] >= 0) {
            const int d = d8[k];
            const int pos = atomicAdd(&lcur[boff + (d >> 6)], 1);
            const unsigned int lo = (unsigned int)(s8[k] | ((d & 63) << 26));
            const unsigned int hi = (unsigned int)__float_as_int(nv8[k]);
            part[pos] = (long long)(((unsigned long long)hi << 32) | lo);
        }
    }
}

// ---------------- pass 2: fused LDS counting-sort + gather --------------------
// Round-14: inner loop RESTORED to the r7/r8 PROVEN 4-deep NAMED-SCALAR form.
// r12/r13 forensics: the e[8]/f[8] ARRAY form went to scratch (VGPR stayed 40,
// WRITE_SIZE 37.5->78.2 MB deterministic, p2 +24us) -- rule #20. Named scalars
// e0..e3/f0..f3 are true registers: WRITE 37.5 MB, 104.5us (r8 measured).
// Cached output stores (nt-store A/B'd ~neutral-to-negative in r12/r13).
__global__ __launch_bounds__(P2_THREADS, 6) void p2_gather_kernel(
        const uint4* __restrict__ user16, const uint4* __restrict__ item16,
        const long long* __restrict__ part, const int* __restrict__ base,
        float* __restrict__ h_user, float* __restrict__ h_item) {
    __shared__ int2 sorted[TILE];        // 32 KB
    __shared__ float acc[RW * D];        // 16 KB
    __shared__ int cnt[RW], offs[RW], cursor[RW], cnt2[RW];
    const int b = blockIdx.x;
    const int tid = threadIdx.x;
    const int lane = tid & 63;
    const int wave = tid >> 6;           // 0..7

    const int E0 = base[b];
    const int E1 = base[b + 1];

    const bool item_side = b < B_UI;
    const uint4* __restrict__ feat = item_side ? user16 : item16;
    const int baseRow = (item_side ? b : b - B_UI) * RW;

    for (int i = tid; i < RW * D; i += P2_THREADS) acc[i] = 0.f;

    for (int bas = E0; bas < E1; bas += TILE) {
        const int tileN = min(TILE, E1 - bas);
        if (tid < RW) cnt[tid] = 0;
        __syncthreads();                           // A: acc/sorted free, cnt zeroed
        int2 v[TILE / P2_THREADS];
#pragma unroll
        for (int k = 0; k < TILE / P2_THREADS; k++) {
            const int t = tid + k * P2_THREADS;
            if (t < tileN) {
                const long long raw = __builtin_nontemporal_load(&part[bas + t]);
                v[k].x = (int)(unsigned int)(raw & 0xffffffffll);
                v[k].y = (int)(unsigned int)((unsigned long long)raw >> 32);
                atomicAdd(&cnt[((unsigned)v[k].x) >> 26], 1);
            }
        }
        __syncthreads();                           // B
        if (tid < RW) {  // wave 0 scans 64 counts
            const int c = cnt[tid];
            int incl = c;
            for (int dd = 1; dd < RW; dd <<= 1) {
                const int u = __shfl_up(incl, dd, 64);
                if (lane >= dd) incl += u;
            }
            offs[tid] = incl - c;
            cursor[tid] = incl - c;
            cnt2[tid] = c;
        }
        __syncthreads();                           // C
#pragma unroll
        for (int k = 0; k < TILE / P2_THREADS; k++) {
            const int t = tid + k * P2_THREADS;
            if (t < tileN) {
                const int r6 = ((unsigned)v[k].x) >> 26;
                const int pos = atomicAdd(&cursor[r6], 1);
                sorted[pos] = v[k];
            }
        }
        __syncthreads();                           // D
        for (int r = wave; r < RW; r += 8) {
            const int s = offs[r], c = cnt2[r];
            if (c == 0) continue;
            const int sub = lane & 7;
            const int g = lane >> 3;
            float a0 = 0, a1 = 0, a2 = 0, a3 = 0, a4 = 0, a5 = 0, a6 = 0, a7 = 0;
            // 4-deep pipeline, NAMED SCALARS (r7/r8 proven; arrays spill).
            // Tail slots: zero-norm dummies (0 * finite == 0, exact no-op).
            for (int j = g; j < c; j += 32) {
                const int2 e0 = sorted[s + j];
                const int2 e1 = (j + 8  < c) ? sorted[s + j + 8]  : make_int2(0, 0);
                const int2 e2 = (j + 16 < c) ? sorted[s + j + 16] : make_int2(0, 0);
                const int2 e3 = (j + 24 < c) ? sorted[s + j + 24] : make_int2(0, 0);
                const uint4 f0 = feat[(e0.x & 0x03FFFFFF) * 8 + sub];
                const uint4 f1 = feat[(e1.x & 0x03FFFFFF) * 8 + sub];
                const uint4 f2 = feat[(e2.x & 0x03FFFFFF) * 8 + sub];
                const uint4 f3 = feat[(e3.x & 0x03FFFFFF) * 8 + sub];
                const float n0 = __int_as_float(e0.y);
                const float n1 = __int_as_float(e1.y);
                const float n2 = __int_as_float(e2.y);
                const float n3 = __int_as_float(e3.y);
                a0 = fmaf(n0, bf16lo(f0.x), a0);
                a1 = fmaf(n0, bf16hi(f0.x), a1);
                a2 = fmaf(n0, bf16lo(f0.y), a2);
                a3 = fmaf(n0, bf16hi(f0.y), a3);
                a4 = fmaf(n0, bf16lo(f0.z), a4);
                a5 = fmaf(n0, bf16hi(f0.z), a5);
                a6 = fmaf(n0, bf16lo(f0.w), a6);
                a7 = fmaf(n0, bf16hi(f0.w), a7);
                a0 = fmaf(n1, bf16lo(f1.x), a0);
                a1 = fmaf(n1, bf16hi(f1.x), a1);
                a2 = fmaf(n1, bf16lo(f1.y), a2);
                a3 = fmaf(n1, bf16hi(f1.y), a3);
                a4 = fmaf(n1, bf16lo(f1.z), a4);
                a5 = fmaf(n1, bf16hi(f1.z), a5);
                a6 = fmaf(n1, bf16lo(f1.w), a6);
                a7 = fmaf(n1, bf16hi(f1.w), a7);
                a0 = fmaf(n2, bf16lo(f2.x), a0);
                a1 = fmaf(n2, bf16hi(f2.x), a1);
                a2 = fmaf(n2, bf16lo(f2.y), a2);
                a3 = fmaf(n2, bf16hi(f2.y), a3);
                a4 = fmaf(n2, bf16lo(f2.z), a4);
                a5 = fmaf(n2, bf16hi(f2.z), a5);
                a6 = fmaf(n2, bf16lo(f2.w), a6);
                a7 = fmaf(n2, bf16hi(f2.w), a7);
                a0 = fmaf(n3, bf16lo(f3.x), a0);
                a1 = fmaf(n3, bf16hi(f3.x), a1);
                a2 = fmaf(n3, bf16lo(f3.y), a2);
                a3 = fmaf(n3, bf16hi(f3.y), a3);
                a4 = fmaf(n3, bf16lo(f3.z), a4);
                a5 = fmaf(n3, bf16hi(f3.z), a5);
                a6 = fmaf(n3, bf16lo(f3.w), a6);
                a7 = fmaf(n3, bf16hi(f3.w), a7);
            }
            // reduce across the 8 edge-groups (lane bits 3..5)
            for (int m = 8; m <= 32; m <<= 1) {
                a0 += __shfl_xor(a0, m, 64);
                a1 += __shfl_xor(a1, m, 64);
                a2 += __shfl_xor(a2, m, 64);
                a3 += __shfl_xor(a3, m, 64);
                a4 += __shfl_xor(a4, m, 64);
                a5 += __shfl_xor(a5, m, 64);
                a6 += __shfl_xor(a6, m, 64);
                a7 += __shfl_xor(a7, m, 64);
            }
            if (lane < 8) {
                float4* ap = (float4*)&acc[r * D + lane * 8];
                float4 q0 = ap[0], q1 = ap[1];
                q0.x += a0; q0.y += a1; q0.z += a2; q0.w += a3;
                q1.x += a4; q1.y += a5; q1.z += a6; q1.w += a7;
                ap[0] = q0; ap[1] = q1;
            }
        }
    }
    __syncthreads();
    // write out 64 rows x 64 floats, coalesced float4, cached
    float* __restrict__ outp = item_side ? h_item : h_user;
    const int limit = item_side ? N_ITEMS : N_USERS;
#pragma unroll
    for (int it = 0; it < 1024 / P2_THREADS; it++) {
        const int i4 = tid + it * P2_THREADS;   // float4 index in [0,1024)
        const int r = (i4 * 4) >> 6;
        const int row = baseRow + r;
        if (row < limit) {
            *(float4*)&outp[(long long)row * D + ((i4 * 4) & 63)] = *(float4*)&acc[i4 * 4];
        }
    }
}

// ---------------- fallback: atomic scatter (round-1 proven) ----------------
__global__ void scatter_rel_kernel(const float* __restrict__ feat,
                                   const float* __restrict__ norm,
                                   const int* __restrict__ src,
                                   const int* __restrict__ dst,
                                   float* __restrict__ out, int n_edges) {
    const int lane = threadIdx.x & 63;
    const int wib = threadIdx.x >> 6;
    const int wpb = blockDim.x >> 6;
    long long e = (long long)blockIdx.x * wpb + wib;
    const long long stride = (long long)gridDim.x * wpb;
    for (; e < n_edges; e += stride) {
        atomicAdd(&out[(long long)dst[e] * D + lane],
                  norm[e] * feat[(long long)src[e] * D + lane]);
    }
}

extern "C" void kernel_launch(void* const* d_in, const int* in_sizes, int n_in,
                              void* d_out, int out_size, void* d_ws, size_t ws_size,
                              hipStream_t stream) {
    const float* user_feat = (const float*)d_in[0];
    const float* item_feat = (const float*)d_in[1];
    const float* norm_ui   = (const float*)d_in[2];
    const float* norm_iu   = (const float*)d_in[3];
    const int*   ui_src    = (const int*)d_in[4];  // user idx
    const int*   ui_dst    = (const int*)d_in[5];  // item idx
    const int*   iu_src    = (const int*)d_in[6];  // item idx
    const int*   iu_dst    = (const int*)d_in[7];  // user idx

    const int n_ui = in_sizes[4];
    const int n_iu = in_sizes[6];
    const int n_total = n_ui + n_iu;

    float* h_user = (float*)d_out;                              // [N_USERS, D]
    float* h_item = (float*)d_out + (long long)N_USERS * D;     // [N_ITEMS, D]

    const int block = 256;
    const int NB_ui = (n_ui + CHUNK - 1) / CHUNK;
    const int NB_iu = (n_iu + CHUNK - 1) / CHUNK;
    const int NCH = NB_ui + NB_iu;

    // ---- workspace layout (totals+gcur0 adjacent -> single memset) ----
    char* ws = (char*)d_ws;
    size_t off = 0;
    int* totals = (int*)(ws + off);  off += align16((size_t)B_TOT * 4);
    int* gcur0  = (int*)(ws + off);  off += align16((size_t)B_TOT * 4);
    int* base   = (int*)(ws + off);  off += align16((size_t)(B_TOT + 1) * 4);
    long long* part = (long long*)(ws + off); off += align16((size_t)n_total * 8);
    unsigned int* user16 = (unsigned int*)(ws + off); off += align16((size_t)N_USERS * D * 2);
    unsigned int* item16 = (unsigned int*)(ws + off); off += align16((size_t)N_ITEMS * D * 2);
    const size_t needed = off;

    if (ws_size < needed) {
        // fallback: atomic-scatter path
        (void)hipMemsetAsync(d_out, 0, (size_t)out_size * sizeof(float), stream);
        const int wpb = block / 64;
        scatter_rel_kernel<<<(n_ui + wpb - 1) / wpb, block, 0, stream>>>(
            user_feat, norm_ui, ui_src, ui_dst, h_item, n_ui);
        scatter_rel_kernel<<<(n_iu + wpb - 1) / wpb, block, 0, stream>>>(
            item_feat, norm_iu, iu_src, iu_dst, h_user, n_iu);
        return;
    }

    // zero totals + gcur0 in one memset (adjacent in layout)
    (void)hipMemsetAsync(totals, 0, ((size_t)align16((size_t)B_TOT * 4) + (size_t)B_TOT * 4), stream);

    // A. fused convert + bucket totals
    convert_count_kernel<<<512, block, 0, stream>>>(
        user_feat, item_feat, user16, item16, ui_dst, iu_dst,
        totals, n_ui, (long long)n_total);

    // B. fused scan + reserve + scatter (grid == NCH, edges register-cached)
    p1_scan_scatter_kernel<<<NCH, SCT_THREADS, 0, stream>>>(
        ui_src, iu_src, ui_dst, iu_dst, norm_ui, norm_iu,
        totals, base, gcur0, part, n_ui, n_iu, NB_ui);

    // C. fused sort+gather, one block per bucket (writes every output row)
    p2_gather_kernel<<<B_TOT, P2_THREADS, 0, stream>>>(
        (const uint4*)user16, (const uint4*)item16, part, base,
        h_user, h_item);
}